// Round 1
// baseline (4233.062 us; speedup 1.0000x reference)
//
#include <hip/hip_runtime.h>
#include <stdint.h>

// LSTM: B=256, T=512, D=128, H=512, C=10
// R10 = R9 minus the flag indirection: "data IS the flag".
// Persistent: 128 blocks x 4 waves. 16 groups x 8 blocks (g=bid&15); group
// owns 16 batches; each wave owns 16 hidden units (64 gate rows), K=640.
// W_ih/W_hh fragments live in the unified VGPR/AGPR file.
// h exchange: 8-slot rotating buffer pre-filled with f16-NaN sentinel
// 0x7F7F (|h|<=1.0 => byte 0x7F can never occur in fresh data). Producers
// fire-and-forget one relaxed-agent 8B store; consumers poll the DATA
// chunks until all 32 are non-sentinel -- the successful poll already has
// the MFMA operands in registers. This removes the producer vmcnt-drain +
// flag store + separate h-load (2 of 3 serialized MALL round trips/step).
// Slot recycling: each lane sentinel-resets its own publish address in the
// slot for h(t+3); the vmcnt(0) issued right before each publish (free --
// nothing is outstanding there) guarantees the reset is globally visible
// before h(t+2) is issued, hence before any consumer can reach t+3's poll.

#define T_STEPS 512
#define BATCH   256
#define DIM     128
#define HID     512
#define NGRP    16
#define BT      16
#define RBUF    8

typedef _Float16 half8 __attribute__((ext_vector_type(8)));
typedef _Float16 half4 __attribute__((ext_vector_type(4)));
typedef float    f32x4 __attribute__((ext_vector_type(4)));

#define SLOT_HALFS (BATCH * HID)
#define WS_NEEDED  (RBUF * SLOT_HALFS * 2)
#define SENT       0x7F7F7F7F7F7F7F7FULL

__device__ __forceinline__ half8 cvt8(f32x4 a, f32x4 b) {
  half8 r;
  r[0]=(_Float16)a[0]; r[1]=(_Float16)a[1]; r[2]=(_Float16)a[2]; r[3]=(_Float16)a[3];
  r[4]=(_Float16)b[0]; r[5]=(_Float16)b[1]; r[6]=(_Float16)b[2]; r[7]=(_Float16)b[3];
  return r;
}
__device__ __forceinline__ half8 load8_cvt(const float* p) {
  const f32x4* q = (const f32x4*)p;
  return cvt8(q[0], q[1]);
}
__device__ __forceinline__ float fsig(float x) {
  return __builtin_amdgcn_rcpf(1.f + __expf(-x));
}
__device__ __forceinline__ float ftanh(float x) {
  return 1.f - 2.f * __builtin_amdgcn_rcpf(1.f + __expf(2.f * x));
}

union h4u { unsigned long long u; half4 h; };
union h8u { unsigned long long u2[2]; half8 h; };

__global__ __launch_bounds__(256, 1) void lstm_persistent(
    const float* __restrict__ X,   const float* __restrict__ Wih,
    const float* __restrict__ Whh, const float* __restrict__ bih,
    const float* __restrict__ bhh, const float* __restrict__ Wlin,
    float* __restrict__ out, _Float16* __restrict__ hbuf)
{
  const int tid  = threadIdx.x;
  const int w    = tid >> 6;
  const int lane = tid & 63;
  const int col  = lane & 15;        // batch-within-group (B/C col), W A-frag row
  const int q    = lane >> 4;        // 0..3
  const int bid  = blockIdx.x;
  const int g    = bid & 15;         // group
  const int blk  = bid >> 4;         // 0..7 within group
  const int J    = blk * 64 + w * 16;   // hidden-unit base owned by this wave
  const int b_my = g * BT + col;     // this lane's batch

  // ---- W fragments into registers (once) ----
  half8 whh[16][4];                  // [k-chunk of 32][gate]
  half8 wih[4][4];
  #pragma unroll
  for (int kc = 0; kc < 16; ++kc)
    #pragma unroll
    for (int mt = 0; mt < 4; ++mt) {
      const int row = mt * HID + J + col;
      whh[kc][mt] = load8_cvt(Whh + (size_t)row * HID + kc * 32 + q * 8);
    }
  #pragma unroll
  for (int xc = 0; xc < 4; ++xc)
    #pragma unroll
    for (int mt = 0; mt < 4; ++mt) {
      const int row = mt * HID + J + col;
      wih[xc][mt] = load8_cvt(Wih + (size_t)row * DIM + xc * 32 + q * 8);
    }

  float bias[4][4], c_st[4], hsum[4];
  #pragma unroll
  for (int mt = 0; mt < 4; ++mt)
    #pragma unroll
    for (int r = 0; r < 4; ++r) {
      const int row = mt * HID + J + q * 4 + r;
      bias[mt][r] = bih[row] + bhh[row];
    }
  #pragma unroll
  for (int r = 0; r < 4; ++r) { c_st[r] = 0.f; hsum[r] = 0.f; }

  const float* Xb = X + (size_t)b_my * T_STEPS * DIM;
  const size_t pub_off = (size_t)b_my * HID + J + q * 4;  // this lane's 8B publish slot offset (halfs)

  // ---- prologue: X(0) prefetch + acc = xp(0) ----
  f32x4 xraw[8];
  #pragma unroll
  for (int xc = 0; xc < 4; ++xc) {
    const f32x4* p = (const f32x4*)(Xb + xc * 32 + q * 8);
    xraw[2 * xc] = p[0]; xraw[2 * xc + 1] = p[1];
  }
  f32x4 acc[4];
  #pragma unroll
  for (int mt = 0; mt < 4; ++mt) acc[mt] = (f32x4){0.f, 0.f, 0.f, 0.f};
  #pragma unroll
  for (int xc = 0; xc < 4; ++xc) {
    half8 xb = cvt8(xraw[2 * xc], xraw[2 * xc + 1]);
    #pragma unroll
    for (int mt = 0; mt < 4; ++mt)
      acc[mt] = __builtin_amdgcn_mfma_f32_16x16x32_f16(wih[xc][mt], xb, acc[mt], 0, 0, 0);
  }

  for (int t = 0; t < T_STEPS; ++t) {
    // issue X(t+1) raw prefetch (clamped; drained by pre-publish vmcnt(0))
    {
      const int tn = (t + 1 < T_STEPS) ? (t + 1) : (T_STEPS - 1);
      const float* xp = Xb + (size_t)tn * DIM + q * 8;
      #pragma unroll
      for (int xc = 0; xc < 4; ++xc) {
        const f32x4* src = (const f32x4*)(xp + xc * 32);
        xraw[2 * xc]     = src[0];
        xraw[2 * xc + 1] = src[1];
      }
    }

    // sentinel-reset the slot that will hold h(t+3) (own address only;
    // fire-and-forget -- ordered ahead of h(t+2) by next step's vmcnt(0),
    // and same-thread same-address order vs our own later data store).
    // Safe to clobber: slot holds h(t-5), consumed by all waves by step t-2.
    {
      unsigned long long* rp = (unsigned long long*)
          (hbuf + (size_t)((t + 3) & (RBUF - 1)) * SLOT_HALFS + pub_off);
      __hip_atomic_store(rp, (unsigned long long)SENT, __ATOMIC_RELAXED,
                         __HIP_MEMORY_SCOPE_AGENT);
    }

    // wait for h(t): poll the data chunks themselves until none is sentinel
    if (t > 0) {
      const unsigned long long* hp = (const unsigned long long*)
          (hbuf + (size_t)(t & (RBUF - 1)) * SLOT_HALFS
                 + (size_t)b_my * HID) + q * 2;
      unsigned long long lo[16], hi[16];
      for (;;) {
        #pragma unroll
        for (int kc = 0; kc < 16; ++kc) {
          lo[kc] = __hip_atomic_load(hp + kc * 8,     __ATOMIC_RELAXED, __HIP_MEMORY_SCOPE_AGENT);
          hi[kc] = __hip_atomic_load(hp + kc * 8 + 1, __ATOMIC_RELAXED, __HIP_MEMORY_SCOPE_AGENT);
        }
        int ok = 1;
        #pragma unroll
        for (int kc = 0; kc < 16; ++kc)
          ok &= (int)(lo[kc] != SENT) & (int)(hi[kc] != SENT);
        if (__all(ok)) break;
      }
      __builtin_amdgcn_sched_barrier(0);  // nothing crosses the spin

      // operands are already in registers -- straight into the h-MFMAs
      #pragma unroll
      for (int kc = 0; kc < 16; ++kc) {
        h8u u; u.u2[0] = lo[kc]; u.u2[1] = hi[kc];
        #pragma unroll
        for (int mt = 0; mt < 4; ++mt)
          acc[mt] = __builtin_amdgcn_mfma_f32_16x16x32_f16(whh[kc][mt], u.h, acc[mt], 0, 0, 0);
      }
    }

    // gates -> c,h ; each lane owns units J+q*4..+3 for batch col
    h4u hv;
    #pragma unroll
    for (int r = 0; r < 4; ++r) {
      const float ig = fsig(acc[0][r] + bias[0][r]);
      const float fg = fsig(acc[1][r] + bias[1][r]);
      const float gg = ftanh(acc[2][r] + bias[2][r]);
      const float og = fsig(acc[3][r] + bias[3][r]);
      const float cc = fg * c_st[r] + ig * gg;
      c_st[r] = cc;
      const float h = og * ftanh(cc);
      hsum[r] += h;
      hv.h[r] = (_Float16)h;
    }

    // publish h(t+1): vmcnt(0) first (essentially free here -- X prefetch
    // and the reset store have had the whole poll+MFMA+gates to complete;
    // it guarantees prior sentinel-resets are globally visible before this
    // data can unblock anyone), then ONE fire-and-forget 8B store. No
    // release drain, no flag.
    asm volatile("s_waitcnt vmcnt(0)" ::: "memory");
    {
      unsigned long long* hw = (unsigned long long*)
          (hbuf + (size_t)((t + 1) & (RBUF - 1)) * SLOT_HALFS + pub_off);
      __hip_atomic_store(hw, hv.u, __ATOMIC_RELAXED, __HIP_MEMORY_SCOPE_AGENT);
    }

    // xp(t+1) NOW -- overlaps our store's propagation and others' polls
    if (t + 1 < T_STEPS) {
      #pragma unroll
      for (int mt = 0; mt < 4; ++mt) acc[mt] = (f32x4){0.f, 0.f, 0.f, 0.f};
      #pragma unroll
      for (int xc = 0; xc < 4; ++xc) {
        half8 xb = cvt8(xraw[2 * xc], xraw[2 * xc + 1]);
        #pragma unroll
        for (int mt = 0; mt < 4; ++mt)
          acc[mt] = __builtin_amdgcn_mfma_f32_16x16x32_f16(wih[xc][mt], xb, acc[mt], 0, 0, 0);
      }
    }
  }

  // epilogue: logits += mean_h * W_lin^T (bias pre-set by init kernel)
  const float inv = 1.0f / (float)T_STEPS;
  float m[4];
  #pragma unroll
  for (int r = 0; r < 4; ++r) m[r] = hsum[r] * inv;
  #pragma unroll
  for (int cls = 0; cls < 10; ++cls) {
    f32x4 wl = *(const f32x4*)(Wlin + (size_t)cls * HID + J + q * 4);
    float p = m[0] * wl[0] + m[1] * wl[1] + m[2] * wl[2] + m[3] * wl[3];
    p += __shfl_xor(p, 16, 64);
    p += __shfl_xor(p, 32, 64);
    if (q == 0) atomicAdd(out + b_my * 10 + cls, p);
  }
}

__global__ void init_out(const float* __restrict__ blin, float* __restrict__ out) {
  const int i = blockIdx.x * blockDim.x + threadIdx.x;
  if (i < BATCH * 10) out[i] = blin[i % 10];
}

extern "C" void kernel_launch(void* const* d_in, const int* in_sizes, int n_in,
                              void* d_out, int out_size, void* d_ws, size_t ws_size,
                              hipStream_t stream) {
  const float* X    = (const float*)d_in[0];
  const float* Wih  = (const float*)d_in[1];
  const float* Whh  = (const float*)d_in[2];
  const float* bih  = (const float*)d_in[3];
  const float* bhh  = (const float*)d_in[4];
  const float* Wlin = (const float*)d_in[5];
  const float* blin = (const float*)d_in[6];
  float* out = (float*)d_out;

  if (ws_size < (size_t)WS_NEEDED) return;

  _Float16* hbuf = (_Float16*)d_ws;

  // 0x7F byte-fill => every f16 is 0x7F7F (NaN). Fresh h has |h| <= 1.0 so
  // no byte of a fresh chunk can be 0x7F -> sentinel is unambiguous.
  hipMemsetAsync(d_ws, 0x7F, WS_NEEDED, stream);
  init_out<<<10, 256, 0, stream>>>(blin, out);
  lstm_persistent<<<128, 256, 0, stream>>>(X, Wih, Whh, bih, bhh, Wlin, out,
                                           hbuf);
}